// Round 8
// baseline (1107.421 us; speedup 1.0000x reference)
//
#include <hip/hip_runtime.h>
#include <hip/hip_bf16.h>
#include <math.h>

// Problem constants (fixed by setup_inputs)
#define BB 2
#define TT 1024
#define DD 2048
#define HH 16
#define DK 128
#define DV 128
#define NG 8
#define GG 16
#define SCALE_Q 0.08838834764831845f  // 128^-0.5

typedef __attribute__((ext_vector_type(8))) short bf16x8;
typedef __attribute__((ext_vector_type(4))) float f32x4;

// bf16 split helpers (RNE)
__device__ __forceinline__ unsigned short f2bf(float v) {
    unsigned u = __float_as_uint(v);
    return (unsigned short)((u + 0x7FFFu + ((u >> 16) & 1u)) >> 16);
}
__device__ __forceinline__ float bf2f(unsigned short h) {
    return __uint_as_float(((unsigned)h) << 16);
}
__device__ __forceinline__ void bsplit(float v, unsigned short& h, unsigned short& l) {
    h = f2bf(v);
    l = f2bf(v - bf2f(h));
}

// ---------------------------------------------------------------------------
// DPP wave64 sum (row_shr 1/2/4/8 + row_bcast 15/31). Lane 63 holds full sum.
// ---------------------------------------------------------------------------
__device__ __forceinline__ float dpp_sum64(float x) {
    x += __int_as_float(__builtin_amdgcn_update_dpp(0, __float_as_int(x), 0x111, 0xf, 0xf, true));  // row_shr:1
    x += __int_as_float(__builtin_amdgcn_update_dpp(0, __float_as_int(x), 0x112, 0xf, 0xf, true));  // row_shr:2
    x += __int_as_float(__builtin_amdgcn_update_dpp(0, __float_as_int(x), 0x114, 0xf, 0xf, true));  // row_shr:4
    x += __int_as_float(__builtin_amdgcn_update_dpp(0, __float_as_int(x), 0x118, 0xf, 0xf, true));  // row_shr:8
    x += __int_as_float(__builtin_amdgcn_update_dpp(0, __float_as_int(x), 0x142, 0xa, 0xf, false)); // row_bcast:15
    x += __int_as_float(__builtin_amdgcn_update_dpp(0, __float_as_int(x), 0x143, 0xc, 0xf, false)); // row_bcast:31
    return x;
}
__device__ __forceinline__ float readlane63(float x) {
    return __int_as_float(__builtin_amdgcn_readlane(__float_as_int(x), 63));
}
__device__ __forceinline__ float f4get(const float4 f, int c) {
    return c == 0 ? f.x : c == 1 ? f.y : c == 2 ? f.z : f.w;
}

// ---------------------------------------------------------------------------
// split: fp32 [n] -> bf16 hi/lo
// ---------------------------------------------------------------------------
__global__ void split_mat(const float* __restrict__ in, unsigned short* __restrict__ oh,
                          unsigned short* __restrict__ ol) {
    const int i0 = (blockIdx.x * 256 + threadIdx.x) * 16;
#pragma unroll
    for (int r = 0; r < 4; ++r) {
        const float4 v = *(const float4*)(in + i0 + r * 4);
        unsigned short h0, l0, h1, l1, h2, l2, h3, l3;
        bsplit(v.x, h0, l0); bsplit(v.y, h1, l1);
        bsplit(v.z, h2, l2); bsplit(v.w, h3, l3);
        short4 hh; hh.x = (short)h0; hh.y = (short)h1; hh.z = (short)h2; hh.w = (short)h3;
        short4 ll; ll.x = (short)l0; ll.y = (short)l1; ll.z = (short)l2; ll.w = (short)l3;
        *(short4*)(oh + i0 + r * 4) = hh;
        *(short4*)(ol + i0 + r * 4) = ll;
    }
}

// ---------------------------------------------------------------------------
// transpose + split: in fp32 [Kin][Nin] -> out bf16 hi/lo [Nin][Kin]
// ---------------------------------------------------------------------------
__global__ void transpose_split(const float* __restrict__ in, unsigned short* __restrict__ oh,
                                unsigned short* __restrict__ ol, int Nin, int Kin) {
    __shared__ float t[64][65];
    const int bx = blockIdx.x, by = blockIdx.y;
    const int tid = threadIdx.x;
    const int c4 = (tid & 15) * 4, r0 = tid >> 4;
#pragma unroll
    for (int rep = 0; rep < 4; ++rep) {
        const int r = r0 + rep * 16;
        const float4 v = *(const float4*)(in + (size_t)(by * 64 + r) * Nin + bx * 64 + c4);
        t[r][c4] = v.x; t[r][c4 + 1] = v.y; t[r][c4 + 2] = v.z; t[r][c4 + 3] = v.w;
    }
    __syncthreads();
#pragma unroll
    for (int rep = 0; rep < 4; ++rep) {
        const int n = r0 + rep * 16;
        short4 hh, ll;
        unsigned short h, l;
        bsplit(t[c4 + 0][n], h, l); hh.x = (short)h; ll.x = (short)l;
        bsplit(t[c4 + 1][n], h, l); hh.y = (short)h; ll.y = (short)l;
        bsplit(t[c4 + 2][n], h, l); hh.z = (short)h; ll.z = (short)l;
        bsplit(t[c4 + 3][n], h, l); hh.w = (short)h; ll.w = (short)l;
        const size_t o = (size_t)(bx * 64 + n) * Kin + by * 64 + c4;
        *(short4*)(oh + o) = hh;
        *(short4*)(ol + o) = ll;
    }
}

// ---------------------------------------------------------------------------
// fp32 transpose per batch: in [B][1024][2048] -> out [B][2048][1024]
// grid: (2048/64, 1024/64, B), 256 threads.
// ---------------------------------------------------------------------------
__global__ void transpose_f32(const float* __restrict__ in, float* __restrict__ out) {
    __shared__ float tl[64][65];
    const int b = blockIdx.z;
    const int c0 = blockIdx.x * 64, t0 = blockIdx.y * 64;
    const int tid = threadIdx.x;
    const int c4 = (tid & 15) * 4, r0 = tid >> 4;
#pragma unroll
    for (int rep = 0; rep < 4; ++rep) {
        const int t = r0 + rep * 16;
        const float4 v = *(const float4*)(in + ((size_t)(b * 1024 + t0 + t)) * 2048 + c0 + c4);
        tl[t][c4] = v.x; tl[t][c4 + 1] = v.y; tl[t][c4 + 2] = v.z; tl[t][c4 + 3] = v.w;
    }
    __syncthreads();
#pragma unroll
    for (int rep = 0; rep < 4; ++rep) {
        const int c = r0 + rep * 16;
        float4 v;
        v.x = tl[c4 + 0][c]; v.y = tl[c4 + 1][c]; v.z = tl[c4 + 2][c]; v.w = tl[c4 + 3][c];
        *(float4*)(out + ((size_t)(b * 2048 + c0 + c)) * 1024 + t0 + c4) = v;
    }
}

// ---------------------------------------------------------------------------
// Split-precision bf16 MFMA GEMM (verified round 4).
// ---------------------------------------------------------------------------
struct GemmArgs {
    const unsigned short* Ah; const unsigned short* Al;
    const unsigned short* Bh[5]; const unsigned short* Bl[5];
    float* C[5];
};

#define AHI 0
#define ALO 8192
#define BHI 16384
#define BLO 24576

#define GL2LDS(g, s) __builtin_amdgcn_global_load_lds( \
    (const __attribute__((address_space(1))) void*)(g), \
    (__attribute__((address_space(3))) void*)(s), 16, 0, 0)

__launch_bounds__(256, 2)
__global__ void gemm_split(GemmArgs p, int fused) {
    __shared__ __attribute__((aligned(16))) char lds[32768];
    const int tid = threadIdx.x;
    const int bx = blockIdx.x, by = blockIdx.y;

    int sel, nloc, ldc;
    if (fused) {
        if (bx < 64) { sel = bx >> 4; nloc = (bx & 15) * 128; ldc = 2048; }
        else         { sel = 4;       nloc = 0;               ldc = 128;  }
    } else { sel = 0; nloc = bx * 128; ldc = 2048; }

    const unsigned short* Asrc_h = p.Ah + (size_t)(by * 128) * 2048;
    const unsigned short* Asrc_l = p.Al + (size_t)(by * 128) * 2048;
    const unsigned short* Bsrc_h = p.Bh[sel] + (size_t)nloc * 2048;
    const unsigned short* Bsrc_l = p.Bl[sel] + (size_t)nloc * 2048;

    const int r0 = tid >> 2, ps0 = tid & 3;
    const int r1 = (tid + 256) >> 2, ps1 = tid & 3;
    const size_t ga0 = (size_t)r0 * 2048 + (size_t)((ps0 ^ ((r0 >> 1) & 3)) * 8);
    const size_t ga1 = (size_t)r1 * 2048 + (size_t)((ps1 ^ ((r1 >> 1) & 3)) * 8);
    const int lb0 = (tid & 192) * 16;
    const int lb1 = (256 + (tid & 192)) * 16;

    const int lane = tid & 63;
    const int l15 = lane & 15, kgrp = lane >> 4;
    const int w = tid >> 6, wm = w >> 1, wn = w & 1;
    const int swz = kgrp ^ ((l15 >> 1) & 3);
    const int fro = l15 * 64 + swz * 16;
    const int aoff = wm * 4096, boff = wn * 4096;

    f32x4 acc[4][4];
#pragma unroll
    for (int i = 0; i < 4; ++i)
#pragma unroll
        for (int j = 0; j < 4; ++j) acc[i][j] = (f32x4){0.f, 0.f, 0.f, 0.f};

    for (int k0 = 0; k0 < 2048; k0 += 32) {
        __syncthreads();
        GL2LDS(Asrc_h + k0 + ga0, lds + AHI + lb0);
        GL2LDS(Asrc_h + k0 + ga1, lds + AHI + lb1);
        GL2LDS(Asrc_l + k0 + ga0, lds + ALO + lb0);
        GL2LDS(Asrc_l + k0 + ga1, lds + ALO + lb1);
        GL2LDS(Bsrc_h + k0 + ga0, lds + BHI + lb0);
        GL2LDS(Bsrc_h + k0 + ga1, lds + BHI + lb1);
        GL2LDS(Bsrc_l + k0 + ga0, lds + BLO + lb0);
        GL2LDS(Bsrc_l + k0 + ga1, lds + BLO + lb1);
        __syncthreads();

        bf16x8 ah[4], al4[4], bh4[4], bl4[4];
#pragma unroll
        for (int f = 0; f < 4; ++f) {
            ah[f]  = *(const bf16x8*)(lds + AHI + aoff + f * 1024 + fro);
            al4[f] = *(const bf16x8*)(lds + ALO + aoff + f * 1024 + fro);
            bh4[f] = *(const bf16x8*)(lds + BHI + boff + f * 1024 + fro);
            bl4[f] = *(const bf16x8*)(lds + BLO + boff + f * 1024 + fro);
        }
#pragma unroll
        for (int i = 0; i < 4; ++i)
#pragma unroll
            for (int j = 0; j < 4; ++j) {
                acc[i][j] = __builtin_amdgcn_mfma_f32_16x16x32_bf16(ah[i],  bh4[j], acc[i][j], 0, 0, 0);
                acc[i][j] = __builtin_amdgcn_mfma_f32_16x16x32_bf16(ah[i],  bl4[j], acc[i][j], 0, 0, 0);
                acc[i][j] = __builtin_amdgcn_mfma_f32_16x16x32_bf16(al4[i], bh4[j], acc[i][j], 0, 0, 0);
            }
    }

    float* cb = p.C[sel];
    const int m0 = by * 128 + wm * 64 + kgrp * 4;
    const int n0 = nloc + wn * 64 + l15;
#pragma unroll
    for (int i = 0; i < 4; ++i)
#pragma unroll
        for (int t = 0; t < 4; ++t) {
            float* cp = cb + (size_t)(m0 + i * 16 + t) * ldc + n0;
#pragma unroll
            for (int j = 0; j < 4; ++j) cp[j * 16] = acc[i][j][t];
        }
}

// ---------------------------------------------------------------------------
// Generic fp32 SGEMM (kept for g1@Wf2 and as full fallback path).
// ---------------------------------------------------------------------------
#define GBM 128
#define GBN 128
#define GBK 16

__launch_bounds__(256)
__global__ void sgemm128(const float* __restrict__ A, const float* __restrict__ B,
                         float* __restrict__ C, int M, int N, int K) {
    __shared__ float As[GBK][GBM + 4];
    __shared__ float Bs[GBK][GBN + 4];

    const int tid = threadIdx.x;
    const int bm = blockIdx.y * GBM;
    const int bn = blockIdx.x * GBN;

    const int arow = tid >> 2;
    const int acol = (tid & 3) << 2;
    const int brow = tid >> 5;
    const int bcol = (tid & 31) << 2;
    const int ty = tid >> 4;
    const int tx = tid & 15;

    float acc[8][8];
#pragma unroll
    for (int i = 0; i < 8; ++i)
#pragma unroll
        for (int j = 0; j < 8; ++j) acc[i][j] = 0.f;

    for (int k0 = 0; k0 < K; k0 += GBK) {
#pragma unroll
        for (int r = 0; r < 2; ++r) {
            const int m = arow + r * 64;
            const float4 av = *(const float4*)(A + (size_t)(bm + m) * K + k0 + acol);
            As[acol + 0][m] = av.x;
            As[acol + 1][m] = av.y;
            As[acol + 2][m] = av.z;
            As[acol + 3][m] = av.w;
        }
#pragma unroll
        for (int r = 0; r < 2; ++r) {
            const int kk = brow + r * 8;
            *(float4*)(&Bs[kk][bcol]) =
                *(const float4*)(B + (size_t)(k0 + kk) * N + bn + bcol);
        }
        __syncthreads();

#pragma unroll
        for (int kk = 0; kk < GBK; ++kk) {
            float a[8], bf[8];
#pragma unroll
            for (int i = 0; i < 8; ++i) a[i] = As[kk][ty * 8 + i];
#pragma unroll
            for (int j = 0; j < 8; ++j) bf[j] = Bs[kk][tx * 8 + j];
#pragma unroll
            for (int i = 0; i < 8; ++i)
#pragma unroll
                for (int j = 0; j < 8; ++j)
                    acc[i][j] = fmaf(a[i], bf[j], acc[i][j]);
        }
        __syncthreads();
    }

#pragma unroll
    for (int i = 0; i < 8; ++i) {
        float* cp = C + (size_t)(bm + ty * 8 + i) * N + bn + tx * 8;
        *(float4*)(cp + 0) = make_float4(acc[i][0], acc[i][1], acc[i][2], acc[i][3]);
        *(float4*)(cp + 4) = make_float4(acc[i][4], acc[i][5], acc[i][6], acc[i][7]);
    }
}

// ---------------------------------------------------------------------------
// Causal depthwise conv1d (K=4) + silu, optional per-head l2norm * scale.
// ---------------------------------------------------------------------------
__global__ void conv_silu_norm(const float* __restrict__ pre, const float* __restrict__ w,
                               float* __restrict__ out, float scale, int do_norm) {
    const int blk = blockIdx.x;
    const int h = blk & 15;
    const int bt = blk >> 4;
    const int t = bt & (TT - 1);
    const int b = bt >> 10;
    const int dk = threadIdx.x;
    const int c = h * 128 + dk;

    const size_t off = ((size_t)(b * TT + t)) * DD + c;
    float acc = 0.f;
#pragma unroll
    for (int j = 0; j < 4; ++j) {
        const int tt = t - 3 + j;
        const float x = (tt >= 0) ? pre[off + (size_t)(j - 3) * DD] : 0.f;
        acc = fmaf(x, w[c * 4 + j], acc);
    }
    float x = acc / (1.f + expf(-acc));  // silu

    if (do_norm) {
        float ss = x * x;
#pragma unroll
        for (int s = 1; s < 64; s <<= 1) ss += __shfl_xor(ss, s, 64);
        __shared__ float red[2];
        if ((threadIdx.x & 63) == 0) red[threadIdx.x >> 6] = ss;
        __syncthreads();
        const float tot = red[0] + red[1];
        x = x * rsqrtf(tot + 1e-6f) * scale;
    }
    out[off] = x;
}

// ---------------------------------------------------------------------------
__global__ void beta_kernel(const float* __restrict__ hid, const float* __restrict__ Wb,
                            float* __restrict__ beta) {
    const int m = blockIdx.x;
    const int t = threadIdx.x;
    const int h = t & 15;
    const int sl = t >> 4;

    const float* hp = hid + (size_t)m * DD + sl * 128;
    const float* wp = Wb + (size_t)sl * 128 * HH + h;
    float p = 0.f;
#pragma unroll 8
    for (int i = 0; i < 128; ++i) p = fmaf(hp[i], wp[i * HH], p);

    __shared__ float red[256];
    red[t] = p;
    __syncthreads();
    if (t < HH) {
        float s = 0.f;
#pragma unroll
        for (int i = 0; i < 16; ++i) s += red[i * 16 + t];
        beta[(size_t)m * HH + t] = 1.f / (1.f + expf(-s));
    }
}

// ---------------------------------------------------------------------------
// decay (fallback layout [b,t,h,g])
// ---------------------------------------------------------------------------
__global__ void decay_kernel(const float* __restrict__ g2, const float* __restrict__ A_log,
                             const float* __restrict__ dt_bias, float* __restrict__ decay) {
    const int idx = blockIdx.x * 256 + threadIdx.x;
    const int g = idx & (NG - 1);
    const int h = (idx >> 3) & (HH - 1);
    const float x = g2[idx] + dt_bias[h * NG + g];
    const float sp = (x > 20.f) ? x : log1pf(expf(x));
    decay[idx] = expf(-expf(A_log[h]) * sp);
}

// ---------------------------------------------------------------------------
// decay, transposed output [b,h,g,t]
// ---------------------------------------------------------------------------
__global__ void decay_kernel_t(const float* __restrict__ g2, const float* __restrict__ A_log,
                               const float* __restrict__ dt_bias, float* __restrict__ dtr) {
    const int idx = blockIdx.x * 256 + threadIdx.x;   // (b,t,h,g)
    const int g = idx & 7, h = (idx >> 3) & 15;
    const int t = (idx >> 7) & 1023, b = idx >> 17;
    const float x = g2[idx] + dt_bias[h * NG + g];
    const float sp = (x > 20.f) ? x : log1pf(expf(x));
    const float d = expf(-expf(A_log[h]) * sp);
    dtr[(((size_t)(b * 16 + h)) * 8 + g) * 1024 + t] = d;
}

// ---------------------------------------------------------------------------
// Gated delta-rule recurrence, time-major inputs.
// kt/qt/vt: [b,h,c,1024] fp32; dtr: [b,h,g,1024]; beta: [b,t,h]; o: [b,t,h,dv].
// One wave per v-column; lane l owns dk {2l, 2l+1}. Chunk of 8 steps loads as
// dwordx4 (t-contiguous) for k/q/decay; v/beta via lane-buffer + readlane
// (lane index is the unrolled constant j). XCD-aware block swizzle groups
// all 32 v-blocks of a (b,h) on one XCD for L2 locality.
// ---------------------------------------------------------------------------
#define CLD(K, Q, D, V, Bf, T0) do {                                           \
    K[0] = *(const float4*)(kp0 + (T0)); K[1] = *(const float4*)(kp0 + (T0) + 4); \
    K[2] = *(const float4*)(kp1 + (T0)); K[3] = *(const float4*)(kp1 + (T0) + 4); \
    Q[0] = *(const float4*)(qp0 + (T0)); Q[1] = *(const float4*)(qp0 + (T0) + 4); \
    Q[2] = *(const float4*)(qp1 + (T0)); Q[3] = *(const float4*)(qp1 + (T0) + 4); \
    D[0] = *(const float4*)(dp + (T0));  D[1] = *(const float4*)(dp + (T0) + 4);  \
    V = vp[(T0)]; Bf = bp[(size_t)(T0) * HH];                                  \
} while (0)

#define CSTEP(K, Q, D, V, Bf, T0) do {                                         \
    _Pragma("unroll")                                                          \
    for (int j = 0; j < 8; ++j) {                                              \
        const float dj = f4get(D[j >> 2], j & 3);                              \
        S0 *= dj; S1 *= dj;                                                    \
        const float kx = f4get(K[j >> 2], j & 3);                              \
        const float ky = f4get(K[2 + (j >> 2)], j & 3);                        \
        float e = fmaf(kx, S0, ky * S1);                                       \
        e = dpp_sum64(e);                                                      \
        const float err = readlane63(e);                                       \
        const float vj = __int_as_float(                                       \
            __builtin_amdgcn_readlane(__float_as_int(V), j));                  \
        const float bj = __int_as_float(                                       \
            __builtin_amdgcn_readlane(__float_as_int(Bf), j));                 \
        const float delta = bj * (vj - err);                                   \
        S0 = fmaf(kx, delta, S0);                                              \
        S1 = fmaf(ky, delta, S1);                                              \
        const float qx = f4get(Q[j >> 2], j & 3);                              \
        const float qy = f4get(Q[2 + (j >> 2)], j & 3);                        \
        float oo = fmaf(qx, S0, qy * S1);                                      \
        oo = dpp_sum64(oo);                                                    \
        if (lane == 63) o[obase + (size_t)((T0) + j) * 2048 + vi] = oo;        \
    }                                                                          \
} while (0)

__launch_bounds__(256, 4)
__global__ void recur_kernel_t(const float* __restrict__ qt, const float* __restrict__ kt,
                               const float* __restrict__ vt, const float* __restrict__ dtr,
                               const float* __restrict__ beta, float* __restrict__ o) {
    const int bid = blockIdx.x;
    const int xcd = bid & 7, idx = bid >> 3;
    const int bh = xcd * 4 + (idx >> 5);   // all 32 v-blocks of a bh share an XCD
    const int vblk = idx & 31;
    const int b = bh >> 4, h = bh & 15;
    const int w = threadIdx.x >> 6;
    const int lane = threadIdx.x & 63;
    const int jl = lane & 7;
    const int vi = vblk * 4 + w;

    const float* kp0 = kt + ((size_t)bh * 128 + 2 * lane) * 1024;
    const float* kp1 = kp0 + 1024;
    const float* qp0 = qt + ((size_t)bh * 128 + 2 * lane) * 1024;
    const float* qp1 = qp0 + 1024;
    const float* vp  = vt + ((size_t)bh * 128 + vi) * 1024 + jl;
    const float* dp  = dtr + ((size_t)bh * 8 + (lane >> 3)) * 1024;
    const float* bp  = beta + ((size_t)b * 1024 + jl) * HH + h;
    const size_t obase = ((size_t)b * 1024 * HH + h) * 128;

    float S0 = 0.f, S1 = 0.f;
    float4 Ka[4], Qa[4], Da[2], Kb[4], Qb[4], Db[2];
    float Va, Bfa, Vb, Bfb;

    CLD(Ka, Qa, Da, Va, Bfa, 0);

#pragma unroll 1
    for (int t0 = 0; t0 < TT; t0 += 16) {
        CLD(Kb, Qb, Db, Vb, Bfb, t0 + 8);
        CSTEP(Ka, Qa, Da, Va, Bfa, t0);
        const int tA = (t0 + 16 < TT) ? (t0 + 16) : t0;  // clamped dummy at end
        CLD(Ka, Qa, Da, Va, Bfa, tA);
        CSTEP(Kb, Qb, Db, Vb, Bfb, t0 + 8);
    }
}

// ---------------------------------------------------------------------------
// Old-layout recurrence (fallback path only).
// ---------------------------------------------------------------------------
__launch_bounds__(256, 4)
__global__ void recur_kernel(const float* __restrict__ q, const float* __restrict__ k,
                             const float* __restrict__ vv, const float* __restrict__ decay,
                             const float* __restrict__ beta, float* __restrict__ o) {
    const int blk = blockIdx.x;
    const int vblk = blk & 31;
    const int bh = blk >> 5;
    const int b = bh >> 4, h = bh & 15;
    const int w = threadIdx.x >> 6;
    const int lane = threadIdx.x & 63;
    const int vi = vblk * 4 + w;

    float S0 = 0.f, S1 = 0.f;
    const size_t strideT = (size_t)HH * DV;
    const size_t strideT2 = strideT >> 1;
    const size_t base = ((size_t)b * TT * HH + h) * DV;

    const float2* kp = (const float2*)(k + base) + lane;
    const float2* qp = (const float2*)(q + base) + lane;
    const float* vp = vv + base + vi;
    const float* bp = beta + (size_t)b * TT * HH + h;
    const float* dp = decay + ((size_t)b * TT * HH + h) * NG + (lane >> 3);

    float2 kv = kp[0], qv = qp[0];
    float vtv = vp[0], bt = bp[0], dt = dp[0];

    for (int t = 0; t < TT; ++t) {
        const float2 kc = kv, qc = qv;
        const float vc = vtv, bc = bt, dc = dt;

        const int tn = (t + 1 < TT) ? (t + 1) : t;
        kv = kp[(size_t)tn * strideT2];
        qv = qp[(size_t)tn * strideT2];
        vtv = vp[(size_t)tn * strideT];
        bt = bp[(size_t)tn * HH];
        dt = dp[(size_t)tn * HH * NG];

        S0 *= dc;
        S1 *= dc;
        float e = fmaf(kc.x, S0, kc.y * S1);
        e = dpp_sum64(e);
        const float err = readlane63(e);
        const float delta = bc * (vc - err);
        S0 = fmaf(kc.x, delta, S0);
        S1 = fmaf(kc.y, delta, S1);
        float oo = fmaf(qc.x, S0, qc.y * S1);
        oo = dpp_sum64(oo);
        if (lane == 63) o[base + (size_t)t * strideT + vi] = oo;
    }
}

// ---------------------------------------------------------------------------
// Gated RMSNorm -> fp32 y (fallback path)
// ---------------------------------------------------------------------------
__global__ void gated_rmsnorm(const float* __restrict__ o,
                              const float* __restrict__ gpre, const float* __restrict__ bg,
                              const float* __restrict__ norm_w, float* __restrict__ y) {
    const int blk = blockIdx.x;
    const int h = blk & 15;
    const int dv = threadIdx.x;
    const size_t off = (size_t)blk * DV + dv;

    const float ov = o[off];
    const float g = gpre[off] + bg[h * 128 + dv];
    const float yv = ov * (g / (1.f + expf(-g)));

    float ss = yv * yv;
#pragma unroll
    for (int s = 1; s < 64; s <<= 1) ss += __shfl_xor(ss, s, 64);
    __shared__ float red[2];
    if ((threadIdx.x & 63) == 0) red[threadIdx.x >> 6] = ss;
    __syncthreads();
    const float mean = (red[0] + red[1]) * (1.f / 128.f);
    y[off] = yv * rsqrtf(mean + 1e-5f) * norm_w[dv];
}

// ---------------------------------------------------------------------------
// Gated RMSNorm -> bf16 hi/lo split y
// ---------------------------------------------------------------------------
__global__ void gated_rmsnorm_split(const float* __restrict__ o,
                                    const float* __restrict__ gpre, const float* __restrict__ bg,
                                    const float* __restrict__ norm_w,
                                    unsigned short* __restrict__ yh,
                                    unsigned short* __restrict__ yl) {
    const int blk = blockIdx.x;
    const int h = blk & 15;
    const int dv = threadIdx.x;
    const size_t off = (size_t)blk * DV + dv;

    const float ov = o[off];
    const float g = gpre[off] + bg[h * 128 + dv];
    const float yv = ov * (g / (1.f + expf(-g)));

    float ss = yv * yv;
#pragma unroll
    for (int s = 1; s < 64; s <<= 1) ss += __shfl_xor(ss, s, 64);
    __shared__ float red[2];
    if ((threadIdx.x & 63) == 0) red[threadIdx.x >> 6] = ss;
    __syncthreads();
    const float mean = (red[0] + red[1]) * (1.f / 128.f);
    const float y = yv * rsqrtf(mean + 1e-5f) * norm_w[dv];
    unsigned short hh, ll;
    bsplit(y, hh, ll);
    yh[off] = hh;
    yl[off] = ll;
}

// ---------------------------------------------------------------------------
extern "C" void kernel_launch(void* const* d_in, const int* in_sizes, int n_in,
                              void* d_out, int out_size, void* d_ws, size_t ws_size,
                              hipStream_t stream) {
    const float* hid    = (const float*)d_in[0];
    const float* Wq     = (const float*)d_in[1];
    const float* Wk     = (const float*)d_in[2];
    const float* Wv     = (const float*)d_in[3];
    const float* conv_q = (const float*)d_in[4];
    const float* conv_k = (const float*)d_in[5];
    const float* conv_v = (const float*)d_in[6];
    const float* Wf1    = (const float*)d_in[7];
    const float* Wf2    = (const float*)d_in[8];
    const float* Wb     = (const float*)d_in[9];
    const float* A_log  = (const float*)d_in[10];
    const float* dt_bias= (const float*)d_in[11];
    const float* Wg     = (const float*)d_in[12];
    const float* bg     = (const float*)d_in[13];
    const float* norm_w = (const float*)d_in[14];
    const float* Wo     = (const float*)d_in[15];
    float* out = (float*)d_out;

    const size_t N1  = (size_t)2048 * 2048;   // 4,194,304 elems
    const size_t N1B = N1 * 4;                 // bytes of one fp32 matrix
    const int M = BB * TT;                     // 2048

    const size_t NEED_NEW = 9 * N1B + 4325376; // ~155.3 MB

    if (ws_size >= NEED_NEW) {
        // ---------------- MFMA split-precision path ----------------
        char* W = (char*)d_ws;
        // region A [0, N1B): hid split; later o (recurrence output)
        unsigned short* hidh = (unsigned short*)W;
        unsigned short* hidl = hidh + N1;
        float* o = (float*)W;
        // region B [N1B, 5*N1B): 8 transposed-weight bf16 arrays;
        // later qn/kn/vn (3*N1B) overlay Wq/Wk/Wv-transposes.
        char* RB = W + N1B;
        unsigned short* Wqth = (unsigned short*)RB;
        unsigned short* Wqtl = Wqth + N1;
        unsigned short* Wkth = Wqtl + N1;
        unsigned short* Wktl = Wkth + N1;
        unsigned short* Wvth = Wktl + N1;
        unsigned short* Wvtl = Wvth + N1;
        unsigned short* Wgth = Wvtl + N1;
        unsigned short* Wgtl = Wgth + N1;
        float* qn = (float*)RB;
        float* kn = qn + N1;
        float* vn = kn + N1;
        // region C [5*N1B, 9*N1B): q/k/v/g pre-activations.
        // Timeline per 16MB slot:
        //   qpre: conv-q input -> qn_t (recur) -> Woth/Wotl (out-gemm)
        //   kpre: conv-k input -> kn_t (recur) -> yh/yl (rmsnorm out)
        //   vpre: conv-v input -> vn_t (recur)
        //   gpre: live until rmsnorm
        char* RC = W + 5 * N1B;
        float* qpre = (float*)RC;
        float* kpre = qpre + N1;
        float* vpre = kpre + N1;
        float* gpre = vpre + N1;
        float* qn_t = qpre;
        float* kn_t = kpre;
        float* vn_t = vpre;
        unsigned short* Woth = (unsigned short*)RC;
        unsigned short* Wotl = Woth + N1;
        unsigned short* yh = (unsigned short*)(RC + N1B);
        unsigned short* yl = yh + N1;
        // region D [9*N1B, ...): small buffers
        char* RD = W + 9 * N1B;
        float* g1b   = (float*)RD;                    // 262144
        float* g2b   = g1b + 262144;                  // 262144
        float* betab = g2b + 262144;                  // 32768
        float* decayb= betab + 32768;                 // 262144 ([b,h,g,t])
        unsigned short* wf1th = (unsigned short*)(decayb + 262144);
        unsigned short* wf1tl = wf1th + 262144;

        // 1. splits / transposes
        split_mat<<<1024, 256, 0, stream>>>(hid, hidh, hidl);
        transpose_split<<<dim3(32, 32), 256, 0, stream>>>(Wq, Wqth, Wqtl, 2048, 2048);
        transpose_split<<<dim3(32, 32), 256, 0, stream>>>(Wk, Wkth, Wktl, 2048, 2048);
        transpose_split<<<dim3(32, 32), 256, 0, stream>>>(Wv, Wvth, Wvtl, 2048, 2048);
        transpose_split<<<dim3(32, 32), 256, 0, stream>>>(Wg, Wgth, Wgtl, 2048, 2048);
        transpose_split<<<dim3(2, 32), 256, 0, stream>>>(Wf1, wf1th, wf1tl, 128, 2048);

        // 2. fused input projections (q,k,v,g, f1)
        GemmArgs fa;
        fa.Ah = hidh; fa.Al = hidl;
        fa.Bh[0] = Wqth; fa.Bl[0] = Wqtl; fa.C[0] = qpre;
        fa.Bh[1] = Wkth; fa.Bl[1] = Wktl; fa.C[1] = kpre;
        fa.Bh[2] = Wvth; fa.Bl[2] = Wvtl; fa.C[2] = vpre;
        fa.Bh[3] = Wgth; fa.Bl[3] = Wgtl; fa.C[3] = gpre;
        fa.Bh[4] = wf1th; fa.Bl[4] = wf1tl; fa.C[4] = g1b;
        gemm_split<<<dim3(65, 16), 256, 0, stream>>>(fa, 1);

        // 3. beta, g2, decay (transposed)
        beta_kernel<<<M, 256, 0, stream>>>(hid, Wb, betab);
        sgemm128<<<dim3(1, 16), 256, 0, stream>>>(g1b, Wf2, g2b, M, 128, 128);
        decay_kernel_t<<<(M * HH * NG) / 256, 256, 0, stream>>>(g2b, A_log, dt_bias, decayb);

        // 4. conv + silu (+ l2norm)  [b,t,c]
        conv_silu_norm<<<M * HH, 128, 0, stream>>>(qpre, conv_q, qn, SCALE_Q, 1);
        conv_silu_norm<<<M * HH, 128, 0, stream>>>(kpre, conv_k, kn, 1.f, 1);
        conv_silu_norm<<<M * HH, 128, 0, stream>>>(vpre, conv_v, vn, 1.f, 0);

        // 5. transpose to time-major [b,c,t] (into dead pre-activation slots)
        transpose_f32<<<dim3(32, 16, 2), 256, 0, stream>>>(qn, qn_t);
        transpose_f32<<<dim3(32, 16, 2), 256, 0, stream>>>(kn, kn_t);
        transpose_f32<<<dim3(32, 16, 2), 256, 0, stream>>>(vn, vn_t);

        // 6. recurrence (o over dead hid split)
        recur_kernel_t<<<BB * HH * (DV / 4), 256, 0, stream>>>(qn_t, kn_t, vn_t, decayb, betab, o);

        // 7. transpose Wo (over dead qn_t)
        transpose_split<<<dim3(32, 32), 256, 0, stream>>>(Wo, Woth, Wotl, 2048, 2048);

        // 8. gated rmsnorm -> y split (over dead kn_t)
        gated_rmsnorm_split<<<M * HH, 128, 0, stream>>>(o, gpre, bg, norm_w, yh, yl);

        // 9. output projection
        GemmArgs oa;
        oa.Ah = yh; oa.Al = yl;
        for (int i = 0; i < 5; ++i) { oa.Bh[i] = Woth; oa.Bl[i] = Wotl; oa.C[i] = out; }
        gemm_split<<<dim3(16, 16), 256, 0, stream>>>(oa, 0);
    } else {
        // ---------------- fallback: fp32 path (round-2 proven) ----------------
        float* ws = (float*)d_ws;
        float* qpre = ws + 0 * N1;
        float* kpre = ws + 1 * N1;
        float* vpre = ws + 2 * N1;
        float* gpre = ws + 3 * N1;
        float* qn   = ws + 4 * N1;
        float* kn   = ws + 5 * N1;
        float* vn   = ws + 6 * N1;
        float* g1b  = ws + 7 * N1;
        float* g2b  = g1b + (size_t)BB * TT * DV;
        float* betab= g2b + (size_t)BB * TT * HH * NG;
        float* decayb = betab + (size_t)BB * TT * HH;
        float* o = qpre;
        float* y = vpre;

        sgemm128<<<dim3(16, 16), 256, 0, stream>>>(hid, Wq, qpre, M, 2048, 2048);
        sgemm128<<<dim3(16, 16), 256, 0, stream>>>(hid, Wk, kpre, M, 2048, 2048);
        sgemm128<<<dim3(16, 16), 256, 0, stream>>>(hid, Wv, vpre, M, 2048, 2048);
        sgemm128<<<dim3(16, 16), 256, 0, stream>>>(hid, Wg, gpre, M, 2048, 2048);
        sgemm128<<<dim3(1, 16), 256, 0, stream>>>(hid, Wf1, g1b, M, 128, 2048);
        sgemm128<<<dim3(1, 16), 256, 0, stream>>>(g1b, Wf2, g2b, M, 128, 128);
        beta_kernel<<<M, 256, 0, stream>>>(hid, Wb, betab);

        conv_silu_norm<<<M * HH, 128, 0, stream>>>(qpre, conv_q, qn, SCALE_Q, 1);
        conv_silu_norm<<<M * HH, 128, 0, stream>>>(kpre, conv_k, kn, 1.f, 1);
        conv_silu_norm<<<M * HH, 128, 0, stream>>>(vpre, conv_v, vn, 1.f, 0);

        decay_kernel<<<(M * HH * NG) / 256, 256, 0, stream>>>(g2b, A_log, dt_bias, decayb);

        recur_kernel<<<BB * HH * (DV / 4), 256, 0, stream>>>(qn, kn, vn, decayb, betab, o);

        gated_rmsnorm<<<M * HH, 128, 0, stream>>>(o, gpre, bg, norm_w, y);

        sgemm128<<<dim3(16, 16), 256, 0, stream>>>(y, Wo, out, M, 2048, 2048);
    }
}

// Round 9
// 869.406 us; speedup vs baseline: 1.2738x; 1.2738x over previous
//
#include <hip/hip_runtime.h>
#include <hip/hip_bf16.h>
#include <math.h>

// Problem constants (fixed by setup_inputs)
#define BB 2
#define TT 1024
#define DD 2048
#define HH 16
#define DK 128
#define DV 128
#define NG 8
#define GG 16
#define SCALE_Q 0.08838834764831845f  // 128^-0.5

typedef __attribute__((ext_vector_type(8))) short bf16x8;
typedef __attribute__((ext_vector_type(4))) float f32x4;

// bf16 split helpers (RNE)
__device__ __forceinline__ unsigned short f2bf(float v) {
    unsigned u = __float_as_uint(v);
    return (unsigned short)((u + 0x7FFFu + ((u >> 16) & 1u)) >> 16);
}
__device__ __forceinline__ float bf2f(unsigned short h) {
    return __uint_as_float(((unsigned)h) << 16);
}
__device__ __forceinline__ void bsplit(float v, unsigned short& h, unsigned short& l) {
    h = f2bf(v);
    l = f2bf(v - bf2f(h));
}

// ---------------------------------------------------------------------------
// DPP wave64 sum (row_shr 1/2/4/8 + row_bcast 15/31). Lane 63 holds full sum.
// ---------------------------------------------------------------------------
__device__ __forceinline__ float dpp_sum64(float x) {
    x += __int_as_float(__builtin_amdgcn_update_dpp(0, __float_as_int(x), 0x111, 0xf, 0xf, true));  // row_shr:1
    x += __int_as_float(__builtin_amdgcn_update_dpp(0, __float_as_int(x), 0x112, 0xf, 0xf, true));  // row_shr:2
    x += __int_as_float(__builtin_amdgcn_update_dpp(0, __float_as_int(x), 0x114, 0xf, 0xf, true));  // row_shr:4
    x += __int_as_float(__builtin_amdgcn_update_dpp(0, __float_as_int(x), 0x118, 0xf, 0xf, true));  // row_shr:8
    x += __int_as_float(__builtin_amdgcn_update_dpp(0, __float_as_int(x), 0x142, 0xa, 0xf, false)); // row_bcast:15
    x += __int_as_float(__builtin_amdgcn_update_dpp(0, __float_as_int(x), 0x143, 0xc, 0xf, false)); // row_bcast:31
    return x;
}
__device__ __forceinline__ float readlane63(float x) {
    return __int_as_float(__builtin_amdgcn_readlane(__float_as_int(x), 63));
}
__device__ __forceinline__ float f4get(const float4 f, int c) {
    return c == 0 ? f.x : c == 1 ? f.y : c == 2 ? f.z : f.w;
}

// ---------------------------------------------------------------------------
// split: fp32 [n] -> bf16 hi/lo
// ---------------------------------------------------------------------------
__global__ void split_mat(const float* __restrict__ in, unsigned short* __restrict__ oh,
                          unsigned short* __restrict__ ol) {
    const int i0 = (blockIdx.x * 256 + threadIdx.x) * 16;
#pragma unroll
    for (int r = 0; r < 4; ++r) {
        const float4 v = *(const float4*)(in + i0 + r * 4);
        unsigned short h0, l0, h1, l1, h2, l2, h3, l3;
        bsplit(v.x, h0, l0); bsplit(v.y, h1, l1);
        bsplit(v.z, h2, l2); bsplit(v.w, h3, l3);
        short4 hh; hh.x = (short)h0; hh.y = (short)h1; hh.z = (short)h2; hh.w = (short)h3;
        short4 ll; ll.x = (short)l0; ll.y = (short)l1; ll.z = (short)l2; ll.w = (short)l3;
        *(short4*)(oh + i0 + r * 4) = hh;
        *(short4*)(ol + i0 + r * 4) = ll;
    }
}

// ---------------------------------------------------------------------------
// transpose + split: in fp32 [Kin][Nin] -> out bf16 hi/lo [Nin][Kin]
// ---------------------------------------------------------------------------
__global__ void transpose_split(const float* __restrict__ in, unsigned short* __restrict__ oh,
                                unsigned short* __restrict__ ol, int Nin, int Kin) {
    __shared__ float t[64][65];
    const int bx = blockIdx.x, by = blockIdx.y;
    const int tid = threadIdx.x;
    const int c4 = (tid & 15) * 4, r0 = tid >> 4;
#pragma unroll
    for (int rep = 0; rep < 4; ++rep) {
        const int r = r0 + rep * 16;
        const float4 v = *(const float4*)(in + (size_t)(by * 64 + r) * Nin + bx * 64 + c4);
        t[r][c4] = v.x; t[r][c4 + 1] = v.y; t[r][c4 + 2] = v.z; t[r][c4 + 3] = v.w;
    }
    __syncthreads();
#pragma unroll
    for (int rep = 0; rep < 4; ++rep) {
        const int n = r0 + rep * 16;
        short4 hh, ll;
        unsigned short h, l;
        bsplit(t[c4 + 0][n], h, l); hh.x = (short)h; ll.x = (short)l;
        bsplit(t[c4 + 1][n], h, l); hh.y = (short)h; ll.y = (short)l;
        bsplit(t[c4 + 2][n], h, l); hh.z = (short)h; ll.z = (short)l;
        bsplit(t[c4 + 3][n], h, l); hh.w = (short)h; ll.w = (short)l;
        const size_t o = (size_t)(bx * 64 + n) * Kin + by * 64 + c4;
        *(short4*)(oh + o) = hh;
        *(short4*)(ol + o) = ll;
    }
}

// ---------------------------------------------------------------------------
// t-tile transpose: in [B][1024][2048] -> out tiled [bh][tblk][cl][8]
// (time in groups of 8 innermost: coalesced chunk loads in the recurrence).
// grid: 32*128 = 4096 blocks (bh, tblk), 256 threads.
// ---------------------------------------------------------------------------
__global__ void transpose_tile(const float* __restrict__ in, float* __restrict__ out) {
    __shared__ float tl[8][128];
    const int blk = blockIdx.x;
    const int bh = blk >> 7, tblk = blk & 127;
    const int b = bh >> 4, h = bh & 15;
    const int tid = threadIdx.x;

    const int tt = tid >> 5, c4 = (tid & 31) * 4;
    const float4 v = *(const float4*)(in + ((size_t)(b * 1024 + tblk * 8 + tt)) * 2048 + h * 128 + c4);
    tl[tt][c4] = v.x; tl[tt][c4 + 1] = v.y; tl[tt][c4 + 2] = v.z; tl[tt][c4 + 3] = v.w;
    __syncthreads();

    const int cl = tid >> 1, tj0 = (tid & 1) * 4;
    float4 w4;
    w4.x = tl[tj0 + 0][cl]; w4.y = tl[tj0 + 1][cl];
    w4.z = tl[tj0 + 2][cl]; w4.w = tl[tj0 + 3][cl];
    *(float4*)(out + ((size_t)blk * 128 + cl) * 8 + tj0) = w4;
}

// ---------------------------------------------------------------------------
// Split-precision bf16 MFMA GEMM (verified round 4).
// ---------------------------------------------------------------------------
struct GemmArgs {
    const unsigned short* Ah; const unsigned short* Al;
    const unsigned short* Bh[5]; const unsigned short* Bl[5];
    float* C[5];
};

#define AHI 0
#define ALO 8192
#define BHI 16384
#define BLO 24576

#define GL2LDS(g, s) __builtin_amdgcn_global_load_lds( \
    (const __attribute__((address_space(1))) void*)(g), \
    (__attribute__((address_space(3))) void*)(s), 16, 0, 0)

__launch_bounds__(256, 2)
__global__ void gemm_split(GemmArgs p, int fused) {
    __shared__ __attribute__((aligned(16))) char lds[32768];
    const int tid = threadIdx.x;
    const int bx = blockIdx.x, by = blockIdx.y;

    int sel, nloc, ldc;
    if (fused) {
        if (bx < 64) { sel = bx >> 4; nloc = (bx & 15) * 128; ldc = 2048; }
        else         { sel = 4;       nloc = 0;               ldc = 128;  }
    } else { sel = 0; nloc = bx * 128; ldc = 2048; }

    const unsigned short* Asrc_h = p.Ah + (size_t)(by * 128) * 2048;
    const unsigned short* Asrc_l = p.Al + (size_t)(by * 128) * 2048;
    const unsigned short* Bsrc_h = p.Bh[sel] + (size_t)nloc * 2048;
    const unsigned short* Bsrc_l = p.Bl[sel] + (size_t)nloc * 2048;

    const int r0 = tid >> 2, ps0 = tid & 3;
    const int r1 = (tid + 256) >> 2, ps1 = tid & 3;
    const size_t ga0 = (size_t)r0 * 2048 + (size_t)((ps0 ^ ((r0 >> 1) & 3)) * 8);
    const size_t ga1 = (size_t)r1 * 2048 + (size_t)((ps1 ^ ((r1 >> 1) & 3)) * 8);
    const int lb0 = (tid & 192) * 16;
    const int lb1 = (256 + (tid & 192)) * 16;

    const int lane = tid & 63;
    const int l15 = lane & 15, kgrp = lane >> 4;
    const int w = tid >> 6, wm = w >> 1, wn = w & 1;
    const int swz = kgrp ^ ((l15 >> 1) & 3);
    const int fro = l15 * 64 + swz * 16;
    const int aoff = wm * 4096, boff = wn * 4096;

    f32x4 acc[4][4];
#pragma unroll
    for (int i = 0; i < 4; ++i)
#pragma unroll
        for (int j = 0; j < 4; ++j) acc[i][j] = (f32x4){0.f, 0.f, 0.f, 0.f};

    for (int k0 = 0; k0 < 2048; k0 += 32) {
        __syncthreads();
        GL2LDS(Asrc_h + k0 + ga0, lds + AHI + lb0);
        GL2LDS(Asrc_h + k0 + ga1, lds + AHI + lb1);
        GL2LDS(Asrc_l + k0 + ga0, lds + ALO + lb0);
        GL2LDS(Asrc_l + k0 + ga1, lds + ALO + lb1);
        GL2LDS(Bsrc_h + k0 + ga0, lds + BHI + lb0);
        GL2LDS(Bsrc_h + k0 + ga1, lds + BHI + lb1);
        GL2LDS(Bsrc_l + k0 + ga0, lds + BLO + lb0);
        GL2LDS(Bsrc_l + k0 + ga1, lds + BLO + lb1);
        __syncthreads();

        bf16x8 ah[4], al4[4], bh4[4], bl4[4];
#pragma unroll
        for (int f = 0; f < 4; ++f) {
            ah[f]  = *(const bf16x8*)(lds + AHI + aoff + f * 1024 + fro);
            al4[f] = *(const bf16x8*)(lds + ALO + aoff + f * 1024 + fro);
            bh4[f] = *(const bf16x8*)(lds + BHI + boff + f * 1024 + fro);
            bl4[f] = *(const bf16x8*)(lds + BLO + boff + f * 1024 + fro);
        }
#pragma unroll
        for (int i = 0; i < 4; ++i)
#pragma unroll
            for (int j = 0; j < 4; ++j) {
                acc[i][j] = __builtin_amdgcn_mfma_f32_16x16x32_bf16(ah[i],  bh4[j], acc[i][j], 0, 0, 0);
                acc[i][j] = __builtin_amdgcn_mfma_f32_16x16x32_bf16(ah[i],  bl4[j], acc[i][j], 0, 0, 0);
                acc[i][j] = __builtin_amdgcn_mfma_f32_16x16x32_bf16(al4[i], bh4[j], acc[i][j], 0, 0, 0);
            }
    }

    float* cb = p.C[sel];
    const int m0 = by * 128 + wm * 64 + kgrp * 4;
    const int n0 = nloc + wn * 64 + l15;
#pragma unroll
    for (int i = 0; i < 4; ++i)
#pragma unroll
        for (int t = 0; t < 4; ++t) {
            float* cp = cb + (size_t)(m0 + i * 16 + t) * ldc + n0;
#pragma unroll
            for (int j = 0; j < 4; ++j) cp[j * 16] = acc[i][j][t];
        }
}

// ---------------------------------------------------------------------------
// Generic fp32 SGEMM (kept for g1@Wf2 and as full fallback path).
// ---------------------------------------------------------------------------
#define GBM 128
#define GBN 128
#define GBK 16

__launch_bounds__(256)
__global__ void sgemm128(const float* __restrict__ A, const float* __restrict__ B,
                         float* __restrict__ C, int M, int N, int K) {
    __shared__ float As[GBK][GBM + 4];
    __shared__ float Bs[GBK][GBN + 4];

    const int tid = threadIdx.x;
    const int bm = blockIdx.y * GBM;
    const int bn = blockIdx.x * GBN;

    const int arow = tid >> 2;
    const int acol = (tid & 3) << 2;
    const int brow = tid >> 5;
    const int bcol = (tid & 31) << 2;
    const int ty = tid >> 4;
    const int tx = tid & 15;

    float acc[8][8];
#pragma unroll
    for (int i = 0; i < 8; ++i)
#pragma unroll
        for (int j = 0; j < 8; ++j) acc[i][j] = 0.f;

    for (int k0 = 0; k0 < K; k0 += GBK) {
#pragma unroll
        for (int r = 0; r < 2; ++r) {
            const int m = arow + r * 64;
            const float4 av = *(const float4*)(A + (size_t)(bm + m) * K + k0 + acol);
            As[acol + 0][m] = av.x;
            As[acol + 1][m] = av.y;
            As[acol + 2][m] = av.z;
            As[acol + 3][m] = av.w;
        }
#pragma unroll
        for (int r = 0; r < 2; ++r) {
            const int kk = brow + r * 8;
            *(float4*)(&Bs[kk][bcol]) =
                *(const float4*)(B + (size_t)(k0 + kk) * N + bn + bcol);
        }
        __syncthreads();

#pragma unroll
        for (int kk = 0; kk < GBK; ++kk) {
            float a[8], bf[8];
#pragma unroll
            for (int i = 0; i < 8; ++i) a[i] = As[kk][ty * 8 + i];
#pragma unroll
            for (int j = 0; j < 8; ++j) bf[j] = Bs[kk][tx * 8 + j];
#pragma unroll
            for (int i = 0; i < 8; ++i)
#pragma unroll
                for (int j = 0; j < 8; ++j)
                    acc[i][j] = fmaf(a[i], bf[j], acc[i][j]);
        }
        __syncthreads();
    }

#pragma unroll
    for (int i = 0; i < 8; ++i) {
        float* cp = C + (size_t)(bm + ty * 8 + i) * N + bn + tx * 8;
        *(float4*)(cp + 0) = make_float4(acc[i][0], acc[i][1], acc[i][2], acc[i][3]);
        *(float4*)(cp + 4) = make_float4(acc[i][4], acc[i][5], acc[i][6], acc[i][7]);
    }
}

// ---------------------------------------------------------------------------
// Causal depthwise conv1d (K=4) + silu, optional per-head l2norm * scale.
// ---------------------------------------------------------------------------
__global__ void conv_silu_norm(const float* __restrict__ pre, const float* __restrict__ w,
                               float* __restrict__ out, float scale, int do_norm) {
    const int blk = blockIdx.x;
    const int h = blk & 15;
    const int bt = blk >> 4;
    const int t = bt & (TT - 1);
    const int b = bt >> 10;
    const int dk = threadIdx.x;
    const int c = h * 128 + dk;

    const size_t off = ((size_t)(b * TT + t)) * DD + c;
    float acc = 0.f;
#pragma unroll
    for (int j = 0; j < 4; ++j) {
        const int tt = t - 3 + j;
        const float x = (tt >= 0) ? pre[off + (size_t)(j - 3) * DD] : 0.f;
        acc = fmaf(x, w[c * 4 + j], acc);
    }
    float x = acc / (1.f + expf(-acc));  // silu

    if (do_norm) {
        float ss = x * x;
#pragma unroll
        for (int s = 1; s < 64; s <<= 1) ss += __shfl_xor(ss, s, 64);
        __shared__ float red[2];
        if ((threadIdx.x & 63) == 0) red[threadIdx.x >> 6] = ss;
        __syncthreads();
        const float tot = red[0] + red[1];
        x = x * rsqrtf(tot + 1e-6f) * scale;
    }
    out[off] = x;
}

// ---------------------------------------------------------------------------
__global__ void beta_kernel(const float* __restrict__ hid, const float* __restrict__ Wb,
                            float* __restrict__ beta) {
    const int m = blockIdx.x;
    const int t = threadIdx.x;
    const int h = t & 15;
    const int sl = t >> 4;

    const float* hp = hid + (size_t)m * DD + sl * 128;
    const float* wp = Wb + (size_t)sl * 128 * HH + h;
    float p = 0.f;
#pragma unroll 8
    for (int i = 0; i < 128; ++i) p = fmaf(hp[i], wp[i * HH], p);

    __shared__ float red[256];
    red[t] = p;
    __syncthreads();
    if (t < HH) {
        float s = 0.f;
#pragma unroll
        for (int i = 0; i < 16; ++i) s += red[i * 16 + t];
        beta[(size_t)m * HH + t] = 1.f / (1.f + expf(-s));
    }
}

// ---------------------------------------------------------------------------
// decay (fallback layout [b,t,h,g])
// ---------------------------------------------------------------------------
__global__ void decay_kernel(const float* __restrict__ g2, const float* __restrict__ A_log,
                             const float* __restrict__ dt_bias, float* __restrict__ decay) {
    const int idx = blockIdx.x * 256 + threadIdx.x;
    const int g = idx & (NG - 1);
    const int h = (idx >> 3) & (HH - 1);
    const float x = g2[idx] + dt_bias[h * NG + g];
    const float sp = (x > 20.f) ? x : log1pf(expf(x));
    decay[idx] = expf(-expf(A_log[h]) * sp);
}

// ---------------------------------------------------------------------------
// decay, t-tiled output [bh][tblk][g][8]
// ---------------------------------------------------------------------------
__global__ void decay_kernel_t(const float* __restrict__ g2, const float* __restrict__ A_log,
                               const float* __restrict__ dt_bias, float* __restrict__ dtr) {
    const int idx = blockIdx.x * 256 + threadIdx.x;   // (b,t,h,g)
    const int g = idx & 7, h = (idx >> 3) & 15;
    const int t = (idx >> 7) & 1023, b = idx >> 17;
    const float x = g2[idx] + dt_bias[h * NG + g];
    const float sp = (x > 20.f) ? x : log1pf(expf(x));
    const float d = expf(-expf(A_log[h]) * sp);
    const int bh = b * 16 + h, tblk = t >> 3, tj = t & 7;
    dtr[((size_t)(bh * 128 + tblk)) * 64 + g * 8 + tj] = d;
}

// ---------------------------------------------------------------------------
// Gated delta-rule recurrence, t-tiled inputs.
// kt/qt/vt tiled [bh][tblk][cl][8] fp32; dtr [bh][tblk][g][8]; beta [b,t,h];
// o [b,t,h,dv]. One wave per v-column; lane l owns dk {2l,2l+1} -> its chunk
// data (2 rows x 8 t) is 64B CONTIGUOUS; the wave's k-load spans one 4KB
// block (perfect coalescing) while staying t-local for L2. v/beta via
// lane-buffer + readlane; decay as two dwordx4 per lane (contiguous).
// XCD-aware block swizzle keeps all 32 v-block waves of a (b,h) on one XCD.
// ---------------------------------------------------------------------------
#define CLD(K, Q, D, V, Bf, T0) do {                                           \
    const float* kpt = kp0 + (size_t)(T0) * 128;                               \
    const float* qpt = qp0 + (size_t)(T0) * 128;                               \
    K[0] = *(const float4*)(kpt);      K[1] = *(const float4*)(kpt + 4);       \
    K[2] = *(const float4*)(kpt + 8);  K[3] = *(const float4*)(kpt + 12);      \
    Q[0] = *(const float4*)(qpt);      Q[1] = *(const float4*)(qpt + 4);       \
    Q[2] = *(const float4*)(qpt + 8);  Q[3] = *(const float4*)(qpt + 12);      \
    D[0] = *(const float4*)(dp + (size_t)(T0) * 8);                            \
    D[1] = *(const float4*)(dp + (size_t)(T0) * 8 + 4);                        \
    V = vp[(size_t)(T0) * 128];                                                \
    Bf = bp[(size_t)(T0) * 16];                                                \
} while (0)

#define CSTEP(K, Q, D, V, Bf, T0) do {                                         \
    _Pragma("unroll")                                                          \
    for (int j = 0; j < 8; ++j) {                                              \
        const float dj = f4get(D[j >> 2], j & 3);                              \
        S0 *= dj; S1 *= dj;                                                    \
        const float kx = f4get(K[j >> 2], j & 3);                              \
        const float ky = f4get(K[2 + (j >> 2)], j & 3);                        \
        float e = fmaf(kx, S0, ky * S1);                                       \
        e = dpp_sum64(e);                                                      \
        const float err = readlane63(e);                                       \
        const float vj = __int_as_float(                                       \
            __builtin_amdgcn_readlane(__float_as_int(V), j));                  \
        const float bj = __int_as_float(                                       \
            __builtin_amdgcn_readlane(__float_as_int(Bf), j));                 \
        const float delta = bj * (vj - err);                                   \
        S0 = fmaf(kx, delta, S0);                                              \
        S1 = fmaf(ky, delta, S1);                                              \
        const float qx = f4get(Q[j >> 2], j & 3);                              \
        const float qy = f4get(Q[2 + (j >> 2)], j & 3);                        \
        float oo = fmaf(qx, S0, qy * S1);                                      \
        oo = dpp_sum64(oo);                                                    \
        if (lane == 63) o[obase + (size_t)((T0) + j) * 2048 + vi] = oo;        \
    }                                                                          \
} while (0)

__launch_bounds__(256, 4)
__global__ void recur_kernel_t(const float* __restrict__ qt, const float* __restrict__ kt,
                               const float* __restrict__ vt, const float* __restrict__ dtr,
                               const float* __restrict__ beta, float* __restrict__ o) {
    const int bid = blockIdx.x;
    const int xcd = bid & 7, idx = bid >> 3;
    const int bh = xcd * 4 + (idx >> 5);   // all 32 v-blocks of a bh share an XCD
    const int vblk = idx & 31;
    const int b = bh >> 4, h = bh & 15;
    const int w = threadIdx.x >> 6;
    const int lane = threadIdx.x & 63;
    const int jl = lane & 7;
    const int vi = vblk * 4 + w;

    // tiled bases: per-bh block = 128 tblk * 128 c * 8 t = 131072 floats
    const float* kp0 = kt + (size_t)bh * 131072 + (size_t)(2 * lane) * 8;
    const float* qp0 = qt + (size_t)bh * 131072 + (size_t)(2 * lane) * 8;
    const float* vp  = vt + (size_t)bh * 131072 + (size_t)vi * 8 + jl;
    const float* dp  = dtr + (size_t)bh * 8192 + (size_t)(lane >> 3) * 8;
    const float* bp  = beta + ((size_t)b * 1024 + jl) * HH + h;
    const size_t obase = ((size_t)b * 1024 * HH + h) * 128;

    float S0 = 0.f, S1 = 0.f;
    float4 Ka[4], Qa[4], Da[2], Kb[4], Qb[4], Db[2];
    float Va, Bfa, Vb, Bfb;

    CLD(Ka, Qa, Da, Va, Bfa, 0);

#pragma unroll 1
    for (int t0 = 0; t0 < TT; t0 += 16) {
        CLD(Kb, Qb, Db, Vb, Bfb, t0 + 8);
        CSTEP(Ka, Qa, Da, Va, Bfa, t0);
        const int tA = (t0 + 16 < TT) ? (t0 + 16) : t0;  // clamped dummy at end
        CLD(Ka, Qa, Da, Va, Bfa, tA);
        CSTEP(Kb, Qb, Db, Vb, Bfb, t0 + 8);
    }
}

// ---------------------------------------------------------------------------
// Old-layout recurrence (fallback path only).
// ---------------------------------------------------------------------------
__launch_bounds__(256, 4)
__global__ void recur_kernel(const float* __restrict__ q, const float* __restrict__ k,
                             const float* __restrict__ vv, const float* __restrict__ decay,
                             const float* __restrict__ beta, float* __restrict__ o) {
    const int blk = blockIdx.x;
    const int vblk = blk & 31;
    const int bh = blk >> 5;
    const int b = bh >> 4, h = bh & 15;
    const int w = threadIdx.x >> 6;
    const int lane = threadIdx.x & 63;
    const int vi = vblk * 4 + w;

    float S0 = 0.f, S1 = 0.f;
    const size_t strideT = (size_t)HH * DV;
    const size_t strideT2 = strideT >> 1;
    const size_t base = ((size_t)b * TT * HH + h) * DV;

    const float2* kp = (const float2*)(k + base) + lane;
    const float2* qp = (const float2*)(q + base) + lane;
    const float* vp = vv + base + vi;
    const float* bp = beta + (size_t)b * TT * HH + h;
    const float* dp = decay + ((size_t)b * TT * HH + h) * NG + (lane >> 3);

    float2 kv = kp[0], qv = qp[0];
    float vtv = vp[0], bt = bp[0], dt = dp[0];

    for (int t = 0; t < TT; ++t) {
        const float2 kc = kv, qc = qv;
        const float vc = vtv, bc = bt, dc = dt;

        const int tn = (t + 1 < TT) ? (t + 1) : t;
        kv = kp[(size_t)tn * strideT2];
        qv = qp[(size_t)tn * strideT2];
        vtv = vp[(size_t)tn * strideT];
        bt = bp[(size_t)tn * HH];
        dt = dp[(size_t)tn * HH * NG];

        S0 *= dc;
        S1 *= dc;
        float e = fmaf(kc.x, S0, kc.y * S1);
        e = dpp_sum64(e);
        const float err = readlane63(e);
        const float delta = bc * (vc - err);
        S0 = fmaf(kc.x, delta, S0);
        S1 = fmaf(kc.y, delta, S1);
        float oo = fmaf(qc.x, S0, qc.y * S1);
        oo = dpp_sum64(oo);
        if (lane == 63) o[base + (size_t)t * strideT + vi] = oo;
    }
}

// ---------------------------------------------------------------------------
// Gated RMSNorm -> fp32 y (fallback path)
// ---------------------------------------------------------------------------
__global__ void gated_rmsnorm(const float* __restrict__ o,
                              const float* __restrict__ gpre, const float* __restrict__ bg,
                              const float* __restrict__ norm_w, float* __restrict__ y) {
    const int blk = blockIdx.x;
    const int h = blk & 15;
    const int dv = threadIdx.x;
    const size_t off = (size_t)blk * DV + dv;

    const float ov = o[off];
    const float g = gpre[off] + bg[h * 128 + dv];
    const float yv = ov * (g / (1.f + expf(-g)));

    float ss = yv * yv;
#pragma unroll
    for (int s = 1; s < 64; s <<= 1) ss += __shfl_xor(ss, s, 64);
    __shared__ float red[2];
    if ((threadIdx.x & 63) == 0) red[threadIdx.x >> 6] = ss;
    __syncthreads();
    const float mean = (red[0] + red[1]) * (1.f / 128.f);
    y[off] = yv * rsqrtf(mean + 1e-5f) * norm_w[dv];
}

// ---------------------------------------------------------------------------
// Gated RMSNorm -> bf16 hi/lo split y
// ---------------------------------------------------------------------------
__global__ void gated_rmsnorm_split(const float* __restrict__ o,
                                    const float* __restrict__ gpre, const float* __restrict__ bg,
                                    const float* __restrict__ norm_w,
                                    unsigned short* __restrict__ yh,
                                    unsigned short* __restrict__ yl) {
    const int blk = blockIdx.x;
    const int h = blk & 15;
    const int dv = threadIdx.x;
    const size_t off = (size_t)blk * DV + dv;

    const float ov = o[off];
    const float g = gpre[off] + bg[h * 128 + dv];
    const float yv = ov * (g / (1.f + expf(-g)));

    float ss = yv * yv;
#pragma unroll
    for (int s = 1; s < 64; s <<= 1) ss += __shfl_xor(ss, s, 64);
    __shared__ float red[2];
    if ((threadIdx.x & 63) == 0) red[threadIdx.x >> 6] = ss;
    __syncthreads();
    const float mean = (red[0] + red[1]) * (1.f / 128.f);
    const float y = yv * rsqrtf(mean + 1e-5f) * norm_w[dv];
    unsigned short hh, ll;
    bsplit(y, hh, ll);
    yh[off] = hh;
    yl[off] = ll;
}

// ---------------------------------------------------------------------------
extern "C" void kernel_launch(void* const* d_in, const int* in_sizes, int n_in,
                              void* d_out, int out_size, void* d_ws, size_t ws_size,
                              hipStream_t stream) {
    const float* hid    = (const float*)d_in[0];
    const float* Wq     = (const float*)d_in[1];
    const float* Wk     = (const float*)d_in[2];
    const float* Wv     = (const float*)d_in[3];
    const float* conv_q = (const float*)d_in[4];
    const float* conv_k = (const float*)d_in[5];
    const float* conv_v = (const float*)d_in[6];
    const float* Wf1    = (const float*)d_in[7];
    const float* Wf2    = (const float*)d_in[8];
    const float* Wb     = (const float*)d_in[9];
    const float* A_log  = (const float*)d_in[10];
    const float* dt_bias= (const float*)d_in[11];
    const float* Wg     = (const float*)d_in[12];
    const float* bg     = (const float*)d_in[13];
    const float* norm_w = (const float*)d_in[14];
    const float* Wo     = (const float*)d_in[15];
    float* out = (float*)d_out;

    const size_t N1  = (size_t)2048 * 2048;   // 4,194,304 elems
    const size_t N1B = N1 * 4;                 // bytes of one fp32 matrix
    const int M = BB * TT;                     // 2048

    const size_t NEED_NEW = 9 * N1B + 4325376; // ~155.3 MB

    if (ws_size >= NEED_NEW) {
        // ---------------- MFMA split-precision path ----------------
        char* W = (char*)d_ws;
        // region A [0, N1B): hid split; later o (recurrence output)
        unsigned short* hidh = (unsigned short*)W;
        unsigned short* hidl = hidh + N1;
        float* o = (float*)W;
        // region B [N1B, 5*N1B): 8 transposed-weight bf16 arrays;
        // later qn/kn/vn (3*N1B) overlay Wq/Wk/Wv-transposes.
        char* RB = W + N1B;
        unsigned short* Wqth = (unsigned short*)RB;
        unsigned short* Wqtl = Wqth + N1;
        unsigned short* Wkth = Wqtl + N1;
        unsigned short* Wktl = Wkth + N1;
        unsigned short* Wvth = Wktl + N1;
        unsigned short* Wvtl = Wvth + N1;
        unsigned short* Wgth = Wvtl + N1;
        unsigned short* Wgtl = Wgth + N1;
        float* qn = (float*)RB;
        float* kn = qn + N1;
        float* vn = kn + N1;
        // region C [5*N1B, 9*N1B): q/k/v/g pre-activations.
        // Timeline per 16MB slot:
        //   qpre: conv-q input -> qn_t (recur) -> Woth/Wotl (out-gemm)
        //   kpre: conv-k input -> kn_t (recur) -> yh/yl (rmsnorm out)
        //   vpre: conv-v input -> vn_t (recur)
        //   gpre: live until rmsnorm
        char* RC = W + 5 * N1B;
        float* qpre = (float*)RC;
        float* kpre = qpre + N1;
        float* vpre = kpre + N1;
        float* gpre = vpre + N1;
        float* qn_t = qpre;
        float* kn_t = kpre;
        float* vn_t = vpre;
        unsigned short* Woth = (unsigned short*)RC;
        unsigned short* Wotl = Woth + N1;
        unsigned short* yh = (unsigned short*)(RC + N1B);
        unsigned short* yl = yh + N1;
        // region D [9*N1B, ...): small buffers
        char* RD = W + 9 * N1B;
        float* g1b   = (float*)RD;                    // 262144
        float* g2b   = g1b + 262144;                  // 262144
        float* betab = g2b + 262144;                  // 32768
        float* decayb= betab + 32768;                 // 262144 (tiled)
        unsigned short* wf1th = (unsigned short*)(decayb + 262144);
        unsigned short* wf1tl = wf1th + 262144;

        // 1. splits / transposes
        split_mat<<<1024, 256, 0, stream>>>(hid, hidh, hidl);
        transpose_split<<<dim3(32, 32), 256, 0, stream>>>(Wq, Wqth, Wqtl, 2048, 2048);
        transpose_split<<<dim3(32, 32), 256, 0, stream>>>(Wk, Wkth, Wktl, 2048, 2048);
        transpose_split<<<dim3(32, 32), 256, 0, stream>>>(Wv, Wvth, Wvtl, 2048, 2048);
        transpose_split<<<dim3(32, 32), 256, 0, stream>>>(Wg, Wgth, Wgtl, 2048, 2048);
        transpose_split<<<dim3(2, 32), 256, 0, stream>>>(Wf1, wf1th, wf1tl, 128, 2048);

        // 2. fused input projections (q,k,v,g, f1)
        GemmArgs fa;
        fa.Ah = hidh; fa.Al = hidl;
        fa.Bh[0] = Wqth; fa.Bl[0] = Wqtl; fa.C[0] = qpre;
        fa.Bh[1] = Wkth; fa.Bl[1] = Wktl; fa.C[1] = kpre;
        fa.Bh[2] = Wvth; fa.Bl[2] = Wvtl; fa.C[2] = vpre;
        fa.Bh[3] = Wgth; fa.Bl[3] = Wgtl; fa.C[3] = gpre;
        fa.Bh[4] = wf1th; fa.Bl[4] = wf1tl; fa.C[4] = g1b;
        gemm_split<<<dim3(65, 16), 256, 0, stream>>>(fa, 1);

        // 3. beta, g2, decay (t-tiled)
        beta_kernel<<<M, 256, 0, stream>>>(hid, Wb, betab);
        sgemm128<<<dim3(1, 16), 256, 0, stream>>>(g1b, Wf2, g2b, M, 128, 128);
        decay_kernel_t<<<(M * HH * NG) / 256, 256, 0, stream>>>(g2b, A_log, dt_bias, decayb);

        // 4. conv + silu (+ l2norm)  [b,t,c]
        conv_silu_norm<<<M * HH, 128, 0, stream>>>(qpre, conv_q, qn, SCALE_Q, 1);
        conv_silu_norm<<<M * HH, 128, 0, stream>>>(kpre, conv_k, kn, 1.f, 1);
        conv_silu_norm<<<M * HH, 128, 0, stream>>>(vpre, conv_v, vn, 1.f, 0);

        // 5. t-tile transpose (into dead pre-activation slots)
        transpose_tile<<<4096, 256, 0, stream>>>(qn, qn_t);
        transpose_tile<<<4096, 256, 0, stream>>>(kn, kn_t);
        transpose_tile<<<4096, 256, 0, stream>>>(vn, vn_t);

        // 6. recurrence (o over dead hid split)
        recur_kernel_t<<<BB * HH * (DV / 4), 256, 0, stream>>>(qn_t, kn_t, vn_t, decayb, betab, o);

        // 7. transpose Wo (over dead qn_t)
        transpose_split<<<dim3(32, 32), 256, 0, stream>>>(Wo, Woth, Wotl, 2048, 2048);

        // 8. gated rmsnorm -> y split (over dead kn_t)
        gated_rmsnorm_split<<<M * HH, 128, 0, stream>>>(o, gpre, bg, norm_w, yh, yl);

        // 9. output projection
        GemmArgs oa;
        oa.Ah = yh; oa.Al = yl;
        for (int i = 0; i < 5; ++i) { oa.Bh[i] = Woth; oa.Bl[i] = Wotl; oa.C[i] = out; }
        gemm_split<<<dim3(16, 16), 256, 0, stream>>>(oa, 0);
    } else {
        // ---------------- fallback: fp32 path (round-2 proven) ----------------
        float* ws = (float*)d_ws;
        float* qpre = ws + 0 * N1;
        float* kpre = ws + 1 * N1;
        float* vpre = ws + 2 * N1;
        float* gpre = ws + 3 * N1;
        float* qn   = ws + 4 * N1;
        float* kn   = ws + 5 * N1;
        float* vn   = ws + 6 * N1;
        float* g1b  = ws + 7 * N1;
        float* g2b  = g1b + (size_t)BB * TT * DV;
        float* betab= g2b + (size_t)BB * TT * HH * NG;
        float* decayb = betab + (size_t)BB * TT * HH;
        float* o = qpre;
        float* y = vpre;

        sgemm128<<<dim3(16, 16), 256, 0, stream>>>(hid, Wq, qpre, M, 2048, 2048);
        sgemm128<<<dim3(16, 16), 256, 0, stream>>>(hid, Wk, kpre, M, 2048, 2048);
        sgemm128<<<dim3(16, 16), 256, 0, stream>>>(hid, Wv, vpre, M, 2048, 2048);
        sgemm128<<<dim3(16, 16), 256, 0, stream>>>(hid, Wg, gpre, M, 2048, 2048);
        sgemm128<<<dim3(1, 16), 256, 0, stream>>>(hid, Wf1, g1b, M, 128, 2048);
        sgemm128<<<dim3(1, 16), 256, 0, stream>>>(g1b, Wf2, g2b, M, 128, 128);
        beta_kernel<<<M, 256, 0, stream>>>(hid, Wb, betab);

        conv_silu_norm<<<M * HH, 128, 0, stream>>>(qpre, conv_q, qn, SCALE_Q, 1);
        conv_silu_norm<<<M * HH, 128, 0, stream>>>(kpre, conv_k, kn, 1.f, 1);
        conv_silu_norm<<<M * HH, 128, 0, stream>>>(vpre, conv_v, vn, 1.f, 0);

        decay_kernel<<<(M * HH * NG) / 256, 256, 0, stream>>>(g2b, A_log, dt_bias, decayb);

        recur_kernel<<<BB * HH * (DV / 4), 256, 0, stream>>>(qn, kn, vn, decayb, betab, o);

        gated_rmsnorm<<<M * HH, 128, 0, stream>>>(o, gpre, bg, norm_w, y);

        sgemm128<<<dim3(16, 16), 256, 0, stream>>>(y, Wo, out, M, 2048, 2048);
    }
}